// Round 3
// baseline (533.323 us; speedup 1.0000x reference)
//
#include <hip/hip_runtime.h>

// Problem constants: B=2, N=4096, NS=32, H=8, HD=32, G=16
constexpr int NSC = 32;   // NS neighbors
constexpr int CC  = 256;  // H*HD channels
constexpr int HDD = 32;   // head dim
constexpr int HH  = 8;    // heads
constexpr int GG  = 16;   // geo features
constexpr int GEO_PAD = 17;

// Math: the Linear(NS,NS)->Linear(NS,1) over the neighbor axis collapses to
//   score[h,d] = sum_s we[s,h,d]*Weff[s] + beff,  Weff[s]=sum_t W2[t]*W1[t,s],
//   beff = dot(W2,b1)+b2.
// weight[s,h] = sum_d we[s,h,d]*score[h,d]; its q-term is constant over s and
// softmax(axis=s) is shift-invariant -> weight'[s,h] = gw[s] - sum_d k*score.
__global__ __launch_bounds__(256, 4)
void geoneigh_att_kernel(const float* __restrict__ q,
                         const float* __restrict__ kng,
                         const float* __restrict__ vng,
                         const float* __restrict__ geo,
                         const float* __restrict__ W1,
                         const float* __restrict__ b1,
                         const float* __restrict__ W2,
                         const float* __restrict__ b2,
                         float* __restrict__ out)
{
    __shared__ float lds_k[NSC * CC];          // 32 KB; tail reused for partials
    __shared__ float lds_score[CC];
    __shared__ float lds_geo[NSC * GEO_PAD];   // +1 pad breaks 16-stride conflicts
    __shared__ float lds_w[NSC * HH];
    __shared__ float lds_attn[NSC * HH];
    __shared__ float lds_weff[NSC];
    __shared__ float lds_sgeo[GG];
    __shared__ float lds_beff[1];

    const int t  = threadIdx.x;
    const int bn = blockIdx.x;
    const size_t tokKV = (size_t)bn * (NSC * CC);
    const float* kp = kng + tokKV;
    const float* vp = vng + tokKV;
    const float* qp = q   + (size_t)bn * CC;
    const float* gp = geo + (size_t)bn * (NSC * GG);

    // ---- stage k into LDS (float4, coalesced) ----
    const float4* kp4 = (const float4*)kp;
    float4* lk4 = (float4*)lds_k;
#pragma unroll
    for (int i = 0; i < 8; ++i) lk4[t + 256 * i] = kp4[t + 256 * i];

    // ---- prefetch v into registers (read-once; 16B/lane) ----
    const int sgrp = t >> 6, c4 = t & 63;     // wave id / float4 column
    const float4* vp4 = (const float4*)vp;
    float4 vreg[8];
#pragma unroll
    for (int kk = 0; kk < 8; ++kk) vreg[kk] = vp4[(sgrp + 4 * kk) * 64 + c4];

    const float qv = qp[t] * 0.17677669529663687f;   // q * HD^-0.5

    if (t < 128) {  // stage geo [32][16] -> padded LDS
        float4 gg = ((const float4*)gp)[t];
        int s = t >> 2, off = (t & 3) * 4;
        float* dst = &lds_geo[s * GEO_PAD + off];
        dst[0] = gg.x; dst[1] = gg.y; dst[2] = gg.z; dst[3] = gg.w;
    }
    if (t < 32) {   // Weff[s] = sum_t W2[t]*W1[t,s]  (W1 is L2-hot, 4KB)
        float acc = 0.f;
#pragma unroll
        for (int tt = 0; tt < 32; ++tt) acc += W2[tt] * W1[tt * 32 + t];
        lds_weff[t] = acc;
    } else if (t == 32) {
        float acc = b2[0];
#pragma unroll
        for (int tt = 0; tt < 32; ++tt) acc += W2[tt] * b1[tt];
        lds_beff[0] = acc;
    }
    __syncthreads();

    // ---- phase A: score[c] = qv*sum(Weff) - sum_s k[s,c]*Weff[s] + beff ----
    const float beff = lds_beff[0];
    float kd = 0.f, wsum = 0.f;
#pragma unroll
    for (int s = 0; s < NSC; ++s) {
        float w = lds_weff[s];
        wsum += w;
        kd += lds_k[s * CC + t] * w;   // consecutive lanes -> 2-way (free)
    }
    lds_score[t] = qv * wsum - kd + beff;

    if (t < GG) {   // head-independent geo score
        float sg = beff;
#pragma unroll
        for (int s = 0; s < NSC; ++s) sg += lds_geo[s * GEO_PAD + t] * lds_weff[s];
        lds_sgeo[t] = sg;
    }
    __syncthreads();

    // ---- phase B: weight'[s,h] = gw[s] - sum_d k[s,h,d]*score[h,d] ----
    {
        const int s = t >> 3, h = t & 7;
        const int kbase = s * CC + h * HDD;
        const int sbase = h * HDD;
        float kw = 0.f;
#pragma unroll
        for (int i = 0; i < HDD; ++i) {
            int d = (i + t) & 31;      // lane rotation: 2-way banks (free)
            kw += lds_k[kbase + d] * lds_score[sbase + d];
        }
        float gws = 0.f;
#pragma unroll
        for (int g = 0; g < GG; ++g) gws += lds_geo[s * GEO_PAD + g] * lds_sgeo[g];
        lds_w[t] = gws - kw;           // index s*8+h == t
    }
    __syncthreads();

    // ---- phase C: softmax over s per head (8 threads, 32 elems each) ----
    if (t < HH) {
        float m = -1e30f;
#pragma unroll
        for (int s = 0; s < NSC; ++s) m = fmaxf(m, lds_w[s * HH + t]);
        float e[NSC];
        float sum = 0.f;
#pragma unroll
        for (int s = 0; s < NSC; ++s) { e[s] = expf(lds_w[s * HH + t] - m); sum += e[s]; }
        float r = 1.f / sum;
#pragma unroll
        for (int s = 0; s < NSC; ++s) lds_attn[s * HH + t] = e[s] * r;
    }
    __syncthreads();

    // ---- phase D: out[h,d] = sum_s attn[s,h]*v[s,h,d] ----
    const int h2 = c4 >> 3;            // head of this float4 column
    float4 acc = make_float4(0.f, 0.f, 0.f, 0.f);
#pragma unroll
    for (int kk = 0; kk < 8; ++kk) {
        float a = lds_attn[(sgrp + 4 * kk) * HH + h2];
        acc.x += a * vreg[kk].x;
        acc.y += a * vreg[kk].y;
        acc.z += a * vreg[kk].z;
        acc.w += a * vreg[kk].w;
    }
    // reduce the 4 s-groups via LDS (reuse lds_k space; k reads are done)
    float4* part4 = (float4*)lds_k;
    part4[sgrp * 64 + c4] = acc;
    __syncthreads();
    if (t < 64) {
        float4 r0 = part4[t], r1 = part4[64 + t], r2 = part4[128 + t], r3 = part4[192 + t];
        float4 o = make_float4(r0.x + r1.x + r2.x + r3.x,
                               r0.y + r1.y + r2.y + r3.y,
                               r0.z + r1.z + r2.z + r3.z,
                               r0.w + r1.w + r2.w + r3.w);
        ((float4*)(out + (size_t)bn * CC))[t] = o;
    }
}

extern "C" void kernel_launch(void* const* d_in, const int* in_sizes, int n_in,
                              void* d_out, int out_size, void* d_ws, size_t ws_size,
                              hipStream_t stream) {
    const float* q   = (const float*)d_in[0];
    const float* kng = (const float*)d_in[1];
    const float* vng = (const float*)d_in[2];
    const float* geo = (const float*)d_in[3];
    const float* W1  = (const float*)d_in[4];
    const float* b1  = (const float*)d_in[5];
    const float* W2  = (const float*)d_in[6];
    const float* b2  = (const float*)d_in[7];
    float* out = (float*)d_out;

    const int tokens = 2 * 4096;   // B*N blocks, one per token
    geoneigh_att_kernel<<<tokens, 256, 0, stream>>>(q, kng, vng, geo, W1, b1, W2, b2, out);
}